// Round 6
// baseline (221.490 us; speedup 1.0000x reference)
//
#include <hip/hip_runtime.h>
#include <hip/hip_bf16.h>

#define N_NODES 50000
#define N_EDGES 800000
#define NUM_GRAPHS 512
#define MAXDEG 64
#define XCONV_BLOCKS 3125   // 50000*128 / (256*8)
#define WT_BLOCKS 128       // weight transpose blocks
#define ZC_BLOCKS 49        // zero-cnt blocks: 49*256*4 = 50176 ints
#define SETUP_BLOCKS (XCONV_BLOCKS + WT_BLOCKS + ZC_BLOCKS)

typedef short short8 __attribute__((ext_vector_type(8)));
typedef unsigned short u16x8 __attribute__((ext_vector_type(8)));
typedef float f32x4 __attribute__((ext_vector_type(4)));

__device__ __forceinline__ unsigned short f2bu(float f) {
    __hip_bfloat16 h = __float2bfloat16(f);
    return *reinterpret_cast<unsigned short*>(&h);
}
__device__ __forceinline__ float bu2f(unsigned short u) {
    unsigned int v = ((unsigned int)u) << 16;
    float f;
    __builtin_memcpy(&f, &v, 4);
    return f;
}

// ---- setup: x -> bf16 (xb), zero sentinels + dinv sentinel, W->bf16^T,
//      zero cnt. Fully parallel, no atomics, no fences. ----
__global__ __launch_bounds__(256) void setup_k(const float* __restrict__ x,
                                               unsigned short* __restrict__ xb,
                                               unsigned short* __restrict__ h1,
                                               float* __restrict__ dinv,
                                               int* __restrict__ cnt,
                                               const float* __restrict__ W1,
                                               const float* __restrict__ W2,
                                               unsigned short* __restrict__ W1t,
                                               unsigned short* __restrict__ W2t) {
    int b = blockIdx.x, t = threadIdx.x;
    if (b < XCONV_BLOCKS) {
        int xi = b;
        if (xi == 0 && t < 64)
            ((unsigned int*)(xb + (size_t)N_NODES * 128))[t] = 0u;
        if (xi == 1 && t < 64)
            ((unsigned int*)(h1 + (size_t)N_NODES * 128))[t] = 0u;
        if (xi == 2 && t == 0) dinv[N_NODES] = 0.f;
        const float* xp = x + (size_t)xi * 2048 + t * 8;
        float4 v0 = *(const float4*)xp;
        float4 v1 = *(const float4*)(xp + 4);
        u16x8 o;
        o[0] = f2bu(v0.x); o[1] = f2bu(v0.y); o[2] = f2bu(v0.z); o[3] = f2bu(v0.w);
        o[4] = f2bu(v1.x); o[5] = f2bu(v1.y); o[6] = f2bu(v1.z); o[7] = f2bu(v1.w);
        *(u16x8*)(xb + (size_t)xi * 2048 + t * 8) = o;
        return;
    }
    if (b < XCONV_BLOCKS + WT_BLOCKS) {
        int wb = b - XCONV_BLOCKS;
        const float* W = wb < 64 ? W1 : W2;
        unsigned short* Wt = wb < 64 ? W1t : W2t;
        int idx = (wb & 63) * 256 + t;
        int k = idx >> 7, n = idx & 127;
        Wt[n * 128 + k] = f2bu(W[idx]);
        return;
    }
    int zi = (b - XCONV_BLOCKS - WT_BLOCKS) * 1024 + t * 4;
    *(int4*)(cnt + zi) = (int4){0, 0, 0, 0};
}

// ---- scatter: adjacency build via global atomics (device-scope default).
//      Order within a row is nondeterministic; sums tolerate it. ----
__global__ __launch_bounds__(256) void scatter_k(const int* __restrict__ ei,
                                                 int* __restrict__ cnt,
                                                 unsigned short* __restrict__ adj) {
    int t = threadIdx.x, b = blockIdx.x;
    int e0 = b * 1024 + t;
#pragma unroll
    for (int k = 0; k < 4; ++k) {
        int e = e0 + k * 256;
        if (e < N_EDGES) {
            int src = ei[e];
            int dst = ei[N_EDGES + e];
            int pos = atomicAdd(&cnt[dst], 1);
            if (pos < MAXDEG - 1) adj[(size_t)dst * MAXDEG + pos] = (unsigned short)src;
        }
    }
}

// ---- finalize: per node self-loop, pad to mult-of-4 with sentinel,
//      cnt[node] = tot4, dinv = rsqrt(deg+1). One thread per node. ----
__global__ __launch_bounds__(256) void finalize_k(unsigned short* __restrict__ adj,
                                                  int* __restrict__ cnt,
                                                  float* __restrict__ dinv) {
    int node = blockIdx.x * 256 + threadIdx.x;
    if (node >= N_NODES) return;
    int cc = cnt[node];
    int ec = cc < MAXDEG - 1 ? cc : MAXDEG - 1;
    adj[(size_t)node * MAXDEG + ec] = (unsigned short)node;  // self loop
    int tot = ec + 1, tot4 = (tot + 3) & ~3;
    for (int s = tot; s < tot4; ++s) adj[(size_t)node * MAXDEG + s] = (unsigned short)N_NODES;
    cnt[node] = tot4;                 // padded entry count (mult of 4)
    dinv[node] = rsqrtf((float)cc + 1.0f);
}

// ---- FUSED layer-1: gather bf16 x rows weighted by dinv[src] (FMA),
//      z = dv * sum -> LDS tile (16 nodes), MFMA with W1^T from L2,
//      h1' = dinv * relu(z + b1); result restaged in LDS for coalesced
//      u16x8 stores. ----
__global__ __launch_bounds__(256) void agg1_fused_k(const unsigned short* __restrict__ xb,
                                                    const unsigned short* __restrict__ adj,
                                                    const int* __restrict__ cnt,
                                                    const float* __restrict__ dinv,
                                                    const float* __restrict__ bias,
                                                    const unsigned short* __restrict__ W1t,
                                                    unsigned short* __restrict__ out) {
    __shared__ unsigned short Az[16][136];   // z rows / result rows (bf16)
    int t = threadIdx.x;
    int wave = t >> 6, lane = t & 63, quad = lane >> 4, fl = lane & 15;
    int nl = wave * 4 + quad;
    int node = blockIdx.x * 16 + nl;         // grid*16 == N_NODES
    int2 pack = ((const int2*)(adj + (size_t)node * MAXDEG))[fl];
    int rounds = cnt[node] >> 2;             // >= 1 (self loop)
    float dv = dinv[node];
    int qb = quad << 4;

    float a[8];
#pragma unroll
    for (int j = 0; j < 8; ++j) a[j] = 0.f;

    int i = 0;
    for (; i + 2 <= rounds; i += 2) {
        unsigned pAx = (unsigned)__shfl(pack.x, qb + i, 64);
        unsigned pAy = (unsigned)__shfl(pack.y, qb + i, 64);
        unsigned pBx = (unsigned)__shfl(pack.x, qb + i + 1, 64);
        unsigned pBy = (unsigned)__shfl(pack.y, qb + i + 1, 64);
        unsigned s0 = pAx & 0xFFFFu, s1 = pAx >> 16;
        unsigned s2 = pAy & 0xFFFFu, s3 = pAy >> 16;
        unsigned s4 = pBx & 0xFFFFu, s5 = pBx >> 16;
        unsigned s6 = pBy & 0xFFFFu, s7 = pBy >> 16;
        float d0 = dinv[s0], d1 = dinv[s1], d2 = dinv[s2], d3 = dinv[s3];
        float d4 = dinv[s4], d5 = dinv[s5], d6 = dinv[s6], d7 = dinv[s7];
        u16x8 v0 = *(const u16x8*)(xb + (size_t)s0 * 128 + fl * 8);
        u16x8 v1 = *(const u16x8*)(xb + (size_t)s1 * 128 + fl * 8);
        u16x8 v2 = *(const u16x8*)(xb + (size_t)s2 * 128 + fl * 8);
        u16x8 v3 = *(const u16x8*)(xb + (size_t)s3 * 128 + fl * 8);
        u16x8 v4 = *(const u16x8*)(xb + (size_t)s4 * 128 + fl * 8);
        u16x8 v5 = *(const u16x8*)(xb + (size_t)s5 * 128 + fl * 8);
        u16x8 v6 = *(const u16x8*)(xb + (size_t)s6 * 128 + fl * 8);
        u16x8 v7 = *(const u16x8*)(xb + (size_t)s7 * 128 + fl * 8);
#pragma unroll
        for (int j = 0; j < 8; ++j) {
            a[j] = fmaf(d0, bu2f(v0[j]), a[j]);
            a[j] = fmaf(d1, bu2f(v1[j]), a[j]);
            a[j] = fmaf(d2, bu2f(v2[j]), a[j]);
            a[j] = fmaf(d3, bu2f(v3[j]), a[j]);
            a[j] = fmaf(d4, bu2f(v4[j]), a[j]);
            a[j] = fmaf(d5, bu2f(v5[j]), a[j]);
            a[j] = fmaf(d6, bu2f(v6[j]), a[j]);
            a[j] = fmaf(d7, bu2f(v7[j]), a[j]);
        }
    }
    if (i < rounds) {
        unsigned px = (unsigned)__shfl(pack.x, qb + i, 64);
        unsigned py = (unsigned)__shfl(pack.y, qb + i, 64);
        unsigned s0 = px & 0xFFFFu, s1 = px >> 16;
        unsigned s2 = py & 0xFFFFu, s3 = py >> 16;
        float d0 = dinv[s0], d1 = dinv[s1], d2 = dinv[s2], d3 = dinv[s3];
        u16x8 v0 = *(const u16x8*)(xb + (size_t)s0 * 128 + fl * 8);
        u16x8 v1 = *(const u16x8*)(xb + (size_t)s1 * 128 + fl * 8);
        u16x8 v2 = *(const u16x8*)(xb + (size_t)s2 * 128 + fl * 8);
        u16x8 v3 = *(const u16x8*)(xb + (size_t)s3 * 128 + fl * 8);
#pragma unroll
        for (int j = 0; j < 8; ++j) {
            a[j] = fmaf(d0, bu2f(v0[j]), a[j]);
            a[j] = fmaf(d1, bu2f(v1[j]), a[j]);
            a[j] = fmaf(d2, bu2f(v2[j]), a[j]);
            a[j] = fmaf(d3, bu2f(v3[j]), a[j]);
        }
    }

    // z row (bf16) into LDS A-tile
    u16x8 zv;
#pragma unroll
    for (int j = 0; j < 8; ++j) zv[j] = f2bu(a[j] * dv);
    *(u16x8*)(&Az[nl][fl * 8]) = zv;
    __syncthreads();

    // GEMM: wave computes all 16 rows x cols [wave*32, wave*32+32)
    short8 af[4];
#pragma unroll
    for (int ks = 0; ks < 4; ++ks)
        af[ks] = *(const short8*)(&Az[fl][ks * 32 + quad * 8]);

    f32x4 acc[2];
    acc[0] = (f32x4){0.f, 0.f, 0.f, 0.f};
    acc[1] = (f32x4){0.f, 0.f, 0.f, 0.f};
#pragma unroll
    for (int ks = 0; ks < 4; ++ks)
#pragma unroll
        for (int ct = 0; ct < 2; ++ct) {
            short8 b = *(const short8*)(W1t + (size_t)(wave * 32 + ct * 16 + fl) * 128 + ks * 32 + quad * 8);
            acc[ct] = __builtin_amdgcn_mfma_f32_16x16x32_bf16(af[ks], b, acc[ct], 0, 0, 0);
        }

    // epilogue: restage h1' rows in LDS, then coalesced u16x8 stores
    __syncthreads();   // all Az reads complete before overwrite
    int colbase = wave * 32;
    float bias0 = bias[colbase + fl];
    float bias1 = bias[colbase + 16 + fl];
    int rowq = quad * 4;
#pragma unroll
    for (int rr = 0; rr < 4; ++rr) {
        float dvr = dinv[blockIdx.x * 16 + rowq + rr];
        Az[rowq + rr][colbase + fl]      = f2bu(fmaxf(acc[0][rr] + bias0, 0.f) * dvr);
        Az[rowq + rr][colbase + 16 + fl] = f2bu(fmaxf(acc[1][rr] + bias1, 0.f) * dvr);
    }
    __syncthreads();
    int row = t >> 4, c8 = t & 15;
    *(u16x8*)(out + (size_t)(blockIdx.x * 16 + row) * 128 + c8 * 8) =
        *(const u16x8*)(&Az[row][c8 * 8]);
}

// ---- FUSED layer-2 + readout: gather h1' (dinv[src] pre-folded),
//      z = dv * sum -> LDS tile, MFMA with W2^T, relu(+b2) dot Wl,
//      in-block reduce -> pnode. NO atomics, NO fences. ----
__global__ __launch_bounds__(256) void agg2_fused_k(const unsigned short* __restrict__ hs,
                                                    const unsigned short* __restrict__ adj,
                                                    const int* __restrict__ cnt,
                                                    const float* __restrict__ dinv,
                                                    const float* __restrict__ bias,
                                                    const unsigned short* __restrict__ W2t,
                                                    const float* __restrict__ Wl,
                                                    float* __restrict__ pnode) {
    __shared__ unsigned short Az[16][136];   // z rows (bf16), padded
    __shared__ float part[4][16];
    int t = threadIdx.x;
    int wave = t >> 6, lane = t & 63, quad = lane >> 4, fl = lane & 15;
    int nl = wave * 4 + quad;
    int node = blockIdx.x * 16 + nl;
    int2 pack = ((const int2*)(adj + (size_t)node * MAXDEG))[fl];
    int rounds = cnt[node] >> 2;
    float dv = dinv[node];
    int qb = quad << 4;

    float a[8];
#pragma unroll
    for (int j = 0; j < 8; ++j) a[j] = 0.f;

    int i = 0;
    for (; i + 2 <= rounds; i += 2) {
        unsigned pAx = (unsigned)__shfl(pack.x, qb + i, 64);
        unsigned pAy = (unsigned)__shfl(pack.y, qb + i, 64);
        unsigned pBx = (unsigned)__shfl(pack.x, qb + i + 1, 64);
        unsigned pBy = (unsigned)__shfl(pack.y, qb + i + 1, 64);
        u16x8 v0 = *(const u16x8*)(hs + (size_t)(pAx & 0xFFFFu) * 128 + fl * 8);
        u16x8 v1 = *(const u16x8*)(hs + (size_t)(pAx >> 16) * 128 + fl * 8);
        u16x8 v2 = *(const u16x8*)(hs + (size_t)(pAy & 0xFFFFu) * 128 + fl * 8);
        u16x8 v3 = *(const u16x8*)(hs + (size_t)(pAy >> 16) * 128 + fl * 8);
        u16x8 v4 = *(const u16x8*)(hs + (size_t)(pBx & 0xFFFFu) * 128 + fl * 8);
        u16x8 v5 = *(const u16x8*)(hs + (size_t)(pBx >> 16) * 128 + fl * 8);
        u16x8 v6 = *(const u16x8*)(hs + (size_t)(pBy & 0xFFFFu) * 128 + fl * 8);
        u16x8 v7 = *(const u16x8*)(hs + (size_t)(pBy >> 16) * 128 + fl * 8);
#pragma unroll
        for (int j = 0; j < 8; ++j)
            a[j] += ((bu2f(v0[j]) + bu2f(v1[j])) + (bu2f(v2[j]) + bu2f(v3[j])))
                  + ((bu2f(v4[j]) + bu2f(v5[j])) + (bu2f(v6[j]) + bu2f(v7[j])));
    }
    if (i < rounds) {
        unsigned px = (unsigned)__shfl(pack.x, qb + i, 64);
        unsigned py = (unsigned)__shfl(pack.y, qb + i, 64);
        u16x8 v0 = *(const u16x8*)(hs + (size_t)(px & 0xFFFFu) * 128 + fl * 8);
        u16x8 v1 = *(const u16x8*)(hs + (size_t)(px >> 16) * 128 + fl * 8);
        u16x8 v2 = *(const u16x8*)(hs + (size_t)(py & 0xFFFFu) * 128 + fl * 8);
        u16x8 v3 = *(const u16x8*)(hs + (size_t)(py >> 16) * 128 + fl * 8);
#pragma unroll
        for (int j = 0; j < 8; ++j)
            a[j] += (bu2f(v0[j]) + bu2f(v1[j])) + (bu2f(v2[j]) + bu2f(v3[j]));
    }

    u16x8 zv;
#pragma unroll
    for (int j = 0; j < 8; ++j) zv[j] = f2bu(a[j] * dv);
    *(u16x8*)(&Az[nl][fl * 8]) = zv;
    __syncthreads();

    short8 af[4];
#pragma unroll
    for (int ks = 0; ks < 4; ++ks)
        af[ks] = *(const short8*)(&Az[fl][ks * 32 + quad * 8]);

    f32x4 acc[2];
    acc[0] = (f32x4){0.f, 0.f, 0.f, 0.f};
    acc[1] = (f32x4){0.f, 0.f, 0.f, 0.f};
#pragma unroll
    for (int ks = 0; ks < 4; ++ks)
#pragma unroll
        for (int ct = 0; ct < 2; ++ct) {
            short8 b = *(const short8*)(W2t + (size_t)(wave * 32 + ct * 16 + fl) * 128 + ks * 32 + quad * 8);
            acc[ct] = __builtin_amdgcn_mfma_f32_16x16x32_bf16(af[ks], b, acc[ct], 0, 0, 0);
        }

    float p[4];
#pragma unroll
    for (int rr = 0; rr < 4; ++rr) {
        float s = 0.f;
#pragma unroll
        for (int ct = 0; ct < 2; ++ct) {
            int col = wave * 32 + ct * 16 + fl;
            s += fmaxf(acc[ct][rr] + bias[col], 0.f) * Wl[col];
        }
        p[rr] = s;
    }
#pragma unroll
    for (int rr = 0; rr < 4; ++rr) {
        p[rr] += __shfl_xor(p[rr], 1, 64);
        p[rr] += __shfl_xor(p[rr], 2, 64);
        p[rr] += __shfl_xor(p[rr], 4, 64);
        p[rr] += __shfl_xor(p[rr], 8, 64);
    }
    if (fl == 0) {
#pragma unroll
        for (int rr = 0; rr < 4; ++rr) part[wave][quad * 4 + rr] = p[rr];
    }
    __syncthreads();
    if (t < 16)
        pnode[blockIdx.x * 16 + t] = part[0][t] + part[1][t] + part[2][t] + part[3][t];
}

// ---- final: one wave per graph; segment-mean of pnode + bias + sigmoid ----
__device__ __forceinline__ int lb(const int* a, int n, int v) {
    int lo = 0, hi = n;
    while (lo < hi) {
        int m = (lo + hi) >> 1;
        if (a[m] < v) lo = m + 1;
        else hi = m;
    }
    return lo;
}

__global__ __launch_bounds__(64) void final_k(const float* __restrict__ pnode,
                                              const int* __restrict__ batch,
                                              const float* __restrict__ bl,
                                              float* __restrict__ out) {
    int g = blockIdx.x, t = threadIdx.x;
    int lo = lb(batch, N_NODES, g), hi = lb(batch, N_NODES, g + 1);
    float s = 0.f;
    for (int r = lo + t; r < hi; r += 64) s += pnode[r];
#pragma unroll
    for (int o = 32; o > 0; o >>= 1) s += __shfl_down(s, o, 64);
    if (t == 0) {
        float cf = (float)(hi - lo);
        float z = s / fmaxf(cf, 1.f) + bl[0];
        out[g] = 1.f / (1.f + expf(-z));
    }
}

extern "C" void kernel_launch(void* const* d_in, const int* in_sizes, int n_in,
                              void* d_out, int out_size, void* d_ws, size_t ws_size,
                              hipStream_t stream) {
    const float* x = (const float*)d_in[0];
    const int* ei = (const int*)d_in[1];
    const int* batch = (const int*)d_in[2];
    const float* W1 = (const float*)d_in[3];
    const float* b1 = (const float*)d_in[4];
    const float* W2 = (const float*)d_in[5];
    const float* b2 = (const float*)d_in[6];
    const float* Wl = (const float*)d_in[7];
    const float* bl = (const float*)d_in[8];
    float* out = (float*)d_out;

    char* ws = (char*)d_ws;
    unsigned short* adj = (unsigned short*)(ws + 0x372000);  // 6.42 MB
    int* cnt = (int*)(ws + 0x992000);                        // 50176 ints
    float* dinv = (float*)(ws + 0x9C3000);                   // (N+1) floats
    unsigned short* W1t = (unsigned short*)(ws + 0x9F4000);  // 32 KB
    unsigned short* W2t = (unsigned short*)(ws + 0x9FC000);  // 32 KB
    float* pnode = (float*)(ws + 0xA04000);                  // 200 KB
    unsigned short* xb = (unsigned short*)(ws + 0xA36000);   // (N+1)x128 bf16
    unsigned short* h1 = (unsigned short*)(ws + 0x1672000);  // (N+1)x128 bf16

    setup_k<<<SETUP_BLOCKS, 256, 0, stream>>>(x, xb, h1, dinv, cnt, W1, W2, W1t, W2t);
    scatter_k<<<(N_EDGES + 1023) / 1024, 256, 0, stream>>>(ei, cnt, adj);
    finalize_k<<<196, 256, 0, stream>>>(adj, cnt, dinv);
    agg1_fused_k<<<N_NODES / 16, 256, 0, stream>>>(xb, adj, cnt, dinv, b1, W1t, h1);
    agg2_fused_k<<<N_NODES / 16, 256, 0, stream>>>(h1, adj, cnt, dinv, b2, W2t, Wl, pnode);
    final_k<<<NUM_GRAPHS, 64, 0, stream>>>(pnode, batch, bl, out);
}

// Round 7
// 188.689 us; speedup vs baseline: 1.1738x; 1.1738x over previous
//
#include <hip/hip_runtime.h>
#include <hip/hip_bf16.h>

#define N_NODES 50000
#define N_EDGES 800000
#define NUM_GRAPHS 512
#define MAXDEG 64
#define EPB 4096            // edges per phase-1 block
#define P1_BLOCKS 196       // ceil(N_EDGES / EPB)
#define NBUCK 256
#define NPB 196             // nodes per bucket; NPB*NBUCK = 50176 >= N_NODES

typedef short short8 __attribute__((ext_vector_type(8)));
typedef unsigned short u16x8 __attribute__((ext_vector_type(8)));
typedef float f32x4 __attribute__((ext_vector_type(4)));

__device__ __forceinline__ unsigned short f2bu(float f) {
    __hip_bfloat16 h = __float2bfloat16(f);
    return *reinterpret_cast<unsigned short*>(&h);
}
__device__ __forceinline__ float bu2f(unsigned short u) {
    unsigned int v = ((unsigned int)u) << 16;
    float f;
    __builtin_memcpy(&f, &v, 4);
    return f;
}

// ---- phase 1: bucket 4096 edges/block by dst/196 in LDS, write staged
//      bucket-ordered packed edges (coalesced) + per-(bucket,block) tables.
//      NO global atomics. Also zeros hs1/h1 sentinel rows. ----
__global__ __launch_bounds__(256) void bin_k(const int* __restrict__ ei,
                                             unsigned int* __restrict__ staging,
                                             int* __restrict__ cnts_tbl,
                                             int* __restrict__ offs_tbl,
                                             unsigned short* __restrict__ hs1,
                                             unsigned short* __restrict__ h1) {
    __shared__ unsigned int st[EPB];          // 16 KB
    __shared__ int cnt[NBUCK], cur[NBUCK], scan[NBUCK];
    int b = blockIdx.x, t = threadIdx.x;
    if (b == 0 && t < 64)
        ((unsigned int*)(hs1 + (size_t)N_NODES * 128))[t] = 0u;
    if (b == 1 && t < 64)
        ((unsigned int*)(h1 + (size_t)N_NODES * 128))[t] = 0u;
    cnt[t] = 0;
    __syncthreads();

    int e0 = b * EPB;
    int srcv[16], dstv[16], bk[16];
#pragma unroll
    for (int k = 0; k < 16; ++k) {
        int e = e0 + k * 256 + t;
        bool ok = e < N_EDGES;
        srcv[k] = ok ? ei[e] : 0;
        dstv[k] = ok ? ei[N_EDGES + e] : 0;
        bk[k] = ok ? (dstv[k] / NPB) : -1;
        if (ok) atomicAdd(&cnt[bk[k]], 1);
    }
    __syncthreads();
    scan[t] = cnt[t];
    __syncthreads();
    for (int off = 1; off < 256; off <<= 1) {
        int u = t >= off ? scan[t - off] : 0;
        __syncthreads();
        scan[t] += u;
        __syncthreads();
    }
    int excl = scan[t] - cnt[t];
    cur[t] = excl;
    cnts_tbl[t * P1_BLOCKS + b] = cnt[t];   // [bucket][block]
    offs_tbl[t * P1_BLOCKS + b] = excl;
    __syncthreads();
#pragma unroll
    for (int k = 0; k < 16; ++k) {
        if (bk[k] >= 0) {
            int pos = atomicAdd(&cur[bk[k]], 1);
            int dl = dstv[k] - bk[k] * NPB;  // < 196, fits 8 bits
            st[pos] = (unsigned int)srcv[k] | ((unsigned int)dl << 16);
        }
    }
    __syncthreads();
    unsigned int* gout = staging + (size_t)b * EPB;
    for (int i = t; i < EPB; i += 256) gout[i] = st[i];
}

// ---- phase 2: bucket b builds padded adjacency for its 196 nodes in LDS
//      (ds atomics), then writes it out coalesced. Fused: W->bf16^T.
//      cnt[node] stores tot4 = padded entry count (incl self loop). ----
__global__ __launch_bounds__(256) void adjbuild_k(const unsigned int* __restrict__ staging,
                                                  const int* __restrict__ cnts_tbl,
                                                  const int* __restrict__ offs_tbl,
                                                  unsigned short* __restrict__ adj,
                                                  int* __restrict__ cnt,
                                                  float* __restrict__ dinv,
                                                  const float* __restrict__ W1,
                                                  const float* __restrict__ W2,
                                                  unsigned short* __restrict__ W1t,
                                                  unsigned short* __restrict__ W2t) {
    int b = blockIdx.x, t = threadIdx.x;
    if (b >= NBUCK) {  // fused weight transpose-convert
        int wb = b - NBUCK;
        const float* W = wb < 64 ? W1 : W2;
        unsigned short* Wt = wb < 64 ? W1t : W2t;
        int idx = (wb & 63) * 256 + t;
        int k = idx >> 7, n = idx & 127;
        Wt[n * 128 + k] = f2bu(W[idx]);
        return;
    }
    __shared__ unsigned short adjL[NPB * MAXDEG];  // 25088 B
    __shared__ int cntL[NPB];
    __shared__ int segStart[P1_BLOCKS + 1];
    __shared__ int segOff[P1_BLOCKS];
    __shared__ int tmp[256];

    if (t < NPB) cntL[t] = 0;
    int c = t < P1_BLOCKS ? cnts_tbl[b * P1_BLOCKS + t] : 0;
    if (t < P1_BLOCKS) segOff[t] = offs_tbl[b * P1_BLOCKS + t];
    tmp[t] = c;
    __syncthreads();
    for (int off = 1; off < 256; off <<= 1) {
        int u = t >= off ? tmp[t - off] : 0;
        __syncthreads();
        tmp[t] += u;
        __syncthreads();
    }
    if (t < P1_BLOCKS) segStart[t] = tmp[t] - c;  // exclusive
    if (t == 0) segStart[P1_BLOCKS] = tmp[P1_BLOCKS - 1];
    __syncthreads();

    int T = segStart[P1_BLOCKS];
    for (int f = t; f < T; f += 256) {
        int lo = 0, hi = P1_BLOCKS;
        while (hi - lo > 1) {
            int m = (lo + hi) >> 1;
            if (segStart[m] <= f) lo = m; else hi = m;
        }
        unsigned int p = staging[(size_t)lo * EPB + segOff[lo] + (f - segStart[lo])];
        int src = p & 0xFFFF;
        int dl = p >> 16;
        int slot = atomicAdd(&cntL[dl], 1);
        if (slot < MAXDEG - 1) adjL[dl * MAXDEG + slot] = (unsigned short)src;
    }
    __syncthreads();

    int nodeBase = b * NPB;
    if (t < NPB) {
        int node = nodeBase + t;
        int cc = cntL[t];
        int ec = cc < MAXDEG - 1 ? cc : MAXDEG - 1;
        adjL[t * MAXDEG + ec] = (unsigned short)node;  // self loop
        int tot = ec + 1, tot4 = (tot + 3) & ~3;
        for (int s = tot; s < tot4; ++s) adjL[t * MAXDEG + s] = (unsigned short)N_NODES;
        if (node < N_NODES) {
            cnt[node] = tot4;                // padded entry count (mult of 4)
            dinv[node] = rsqrtf((float)cc + 1.0f);
        }
    }
    __syncthreads();
    unsigned int* g = (unsigned int*)(adj + (size_t)nodeBase * MAXDEG);
    const unsigned int* l = (const unsigned int*)adjL;
    for (int i = t; i < NPB * MAXDEG / 2; i += 256) g[i] = l[i];
}

// ---- GEMM: C[r][c] = bf16( dinv[r] * sum_k A[r][k]*W[k][c] ), 128 rows/block.
//      Epilogue restages the C-tile in LDS (reusing Wl) for coalesced
//      u16x8 stores. ----
template <bool F32A>
__global__ __launch_bounds__(256) void gemm_k(const void* __restrict__ Ap,
                                              const unsigned short* __restrict__ Wt,
                                              const float* __restrict__ dinv,
                                              unsigned short* __restrict__ C) {
    __shared__ unsigned short Wl[128 * 136];   // weights, later reused as C-tile
    int t = threadIdx.x;
    for (int idx = t; idx < 2048; idx += 256) {
        int n = idx >> 4, c = idx & 15;
        *(u16x8*)(Wl + n * 136 + c * 8) = *(const u16x8*)(Wt + n * 128 + c * 8);
    }
    __syncthreads();

    int wave = t >> 6, lane = t & 63, quad = lane >> 4, ln = lane & 15;
    int rb = blockIdx.x * 128 + wave * 16;

    short8 a[2][4];
#pragma unroll
    for (int mt = 0; mt < 2; ++mt) {
        int r = rb + mt * 64 + ln;
        r = r < N_NODES ? r : N_NODES - 1;
        if (F32A) {
            const float* arow = (const float*)Ap + (size_t)r * 128 + quad * 8;
#pragma unroll
            for (int ks = 0; ks < 4; ++ks) {
                float4 v0 = *(const float4*)(arow + ks * 32);
                float4 v1 = *(const float4*)(arow + ks * 32 + 4);
                short8 av;
                av[0] = (short)f2bu(v0.x); av[1] = (short)f2bu(v0.y);
                av[2] = (short)f2bu(v0.z); av[3] = (short)f2bu(v0.w);
                av[4] = (short)f2bu(v1.x); av[5] = (short)f2bu(v1.y);
                av[6] = (short)f2bu(v1.z); av[7] = (short)f2bu(v1.w);
                a[mt][ks] = av;
            }
        } else {
            const unsigned short* arow = (const unsigned short*)Ap + (size_t)r * 128 + quad * 8;
#pragma unroll
            for (int ks = 0; ks < 4; ++ks) a[mt][ks] = *(const short8*)(arow + ks * 32);
        }
    }

    f32x4 acc[2][8];
#pragma unroll
    for (int mt = 0; mt < 2; ++mt)
#pragma unroll
        for (int ct = 0; ct < 8; ++ct) acc[mt][ct] = (f32x4){0.f, 0.f, 0.f, 0.f};

#pragma unroll
    for (int ks = 0; ks < 4; ++ks)
#pragma unroll
        for (int ct = 0; ct < 8; ++ct) {
            short8 b = *(const short8*)(Wl + (ct * 16 + ln) * 136 + ks * 32 + quad * 8);
            acc[0][ct] = __builtin_amdgcn_mfma_f32_16x16x32_bf16(a[0][ks], b, acc[0][ct], 0, 0, 0);
            acc[1][ct] = __builtin_amdgcn_mfma_f32_16x16x32_bf16(a[1][ks], b, acc[1][ct], 0, 0, 0);
        }

    // ---- epilogue: restage C-tile into Wl (all weight reads done), then
    //      coalesced u16x8 stores. Cb[row][col] at stride 132 u16. ----
    __syncthreads();
    unsigned short* Cb = Wl;   // 128*132 = 16896 u16 <= 128*136
#pragma unroll
    for (int mt = 0; mt < 2; ++mt) {
#pragma unroll
        for (int rr = 0; rr < 4; ++rr) {
            int rl = wave * 16 + mt * 64 + quad * 4 + rr;   // local row 0..127
            int rg = blockIdx.x * 128 + rl;
            float dv = dinv[rg < N_NODES ? rg : 0];
#pragma unroll
            for (int ct = 0; ct < 8; ++ct)
                Cb[rl * 132 + ct * 16 + ln] = f2bu(acc[mt][ct][rr] * dv);
        }
    }
    __syncthreads();
    for (int i = t; i < 128 * 16; i += 256) {
        int row = i >> 4, c8 = i & 15;
        int rg = blockIdx.x * 128 + row;
        if (rg < N_NODES)
            *(u16x8*)(C + (size_t)rg * 128 + c8 * 8) = *(const u16x8*)(&Cb[row * 132 + c8 * 8]);
    }
}

// ---- layer-1 aggregation: ONE node per quad (4 nodes/wave, 16/block).
//      Output h1' = dinv[node] * relu(z + b1)  (dinv pre-folded for layer 2). ----
__global__ __launch_bounds__(256) void agg1_k(const unsigned short* __restrict__ hs,
                                              const unsigned short* __restrict__ adj,
                                              const int* __restrict__ cnt,
                                              const float* __restrict__ dinv,
                                              const float* __restrict__ bias,
                                              unsigned short* __restrict__ out) {
    int t = threadIdx.x;
    int wave = t >> 6, lane = t & 63, quad = lane >> 4, fl = lane & 15;
    int node = blockIdx.x * 16 + wave * 4 + quad;      // grid*16 == N_NODES
    int2 pack = ((const int2*)(adj + (size_t)node * MAXDEG))[fl];
    int rounds = cnt[node] >> 2;                       // >= 1 (self loop)
    float dv = dinv[node];
    float4 b0 = *(const float4*)(bias + fl * 8);
    float4 b1 = *(const float4*)(bias + fl * 8 + 4);
    int qb = quad << 4;

    float a[8];
#pragma unroll
    for (int j = 0; j < 8; ++j) a[j] = 0.f;

    int i = 0;
    for (; i + 2 <= rounds; i += 2) {
        unsigned pAx = (unsigned)__shfl(pack.x, qb + i, 64);
        unsigned pAy = (unsigned)__shfl(pack.y, qb + i, 64);
        unsigned pBx = (unsigned)__shfl(pack.x, qb + i + 1, 64);
        unsigned pBy = (unsigned)__shfl(pack.y, qb + i + 1, 64);
        u16x8 v0 = *(const u16x8*)(hs + (size_t)(pAx & 0xFFFFu) * 128 + fl * 8);
        u16x8 v1 = *(const u16x8*)(hs + (size_t)(pAx >> 16) * 128 + fl * 8);
        u16x8 v2 = *(const u16x8*)(hs + (size_t)(pAy & 0xFFFFu) * 128 + fl * 8);
        u16x8 v3 = *(const u16x8*)(hs + (size_t)(pAy >> 16) * 128 + fl * 8);
        u16x8 v4 = *(const u16x8*)(hs + (size_t)(pBx & 0xFFFFu) * 128 + fl * 8);
        u16x8 v5 = *(const u16x8*)(hs + (size_t)(pBx >> 16) * 128 + fl * 8);
        u16x8 v6 = *(const u16x8*)(hs + (size_t)(pBy & 0xFFFFu) * 128 + fl * 8);
        u16x8 v7 = *(const u16x8*)(hs + (size_t)(pBy >> 16) * 128 + fl * 8);
#pragma unroll
        for (int j = 0; j < 8; ++j)
            a[j] += ((bu2f(v0[j]) + bu2f(v1[j])) + (bu2f(v2[j]) + bu2f(v3[j])))
                  + ((bu2f(v4[j]) + bu2f(v5[j])) + (bu2f(v6[j]) + bu2f(v7[j])));
    }
    if (i < rounds) {
        unsigned px = (unsigned)__shfl(pack.x, qb + i, 64);
        unsigned py = (unsigned)__shfl(pack.y, qb + i, 64);
        u16x8 v0 = *(const u16x8*)(hs + (size_t)(px & 0xFFFFu) * 128 + fl * 8);
        u16x8 v1 = *(const u16x8*)(hs + (size_t)(px >> 16) * 128 + fl * 8);
        u16x8 v2 = *(const u16x8*)(hs + (size_t)(py & 0xFFFFu) * 128 + fl * 8);
        u16x8 v3 = *(const u16x8*)(hs + (size_t)(py >> 16) * 128 + fl * 8);
#pragma unroll
        for (int j = 0; j < 8; ++j)
            a[j] += (bu2f(v0[j]) + bu2f(v1[j])) + (bu2f(v2[j]) + bu2f(v3[j]));
    }

    u16x8 o;
    o[0] = f2bu(fmaxf(a[0] * dv + b0.x, 0.f) * dv);
    o[1] = f2bu(fmaxf(a[1] * dv + b0.y, 0.f) * dv);
    o[2] = f2bu(fmaxf(a[2] * dv + b0.z, 0.f) * dv);
    o[3] = f2bu(fmaxf(a[3] * dv + b0.w, 0.f) * dv);
    o[4] = f2bu(fmaxf(a[4] * dv + b1.x, 0.f) * dv);
    o[5] = f2bu(fmaxf(a[5] * dv + b1.y, 0.f) * dv);
    o[6] = f2bu(fmaxf(a[6] * dv + b1.z, 0.f) * dv);
    o[7] = f2bu(fmaxf(a[7] * dv + b1.w, 0.f) * dv);
    *(u16x8*)(out + (size_t)node * 128 + fl * 8) = o;
}

// ---- FUSED layer-2 + readout: gather h1' (dinv[src] pre-folded),
//      z = dv * sum -> LDS tile, MFMA with W2^T, relu(+b2) dot Wl,
//      in-block reduce -> pnode. ----
__global__ __launch_bounds__(256) void agg2_fused_k(const unsigned short* __restrict__ hs,
                                                    const unsigned short* __restrict__ adj,
                                                    const int* __restrict__ cnt,
                                                    const float* __restrict__ dinv,
                                                    const float* __restrict__ bias,
                                                    const unsigned short* __restrict__ W2t,
                                                    const float* __restrict__ Wl,
                                                    float* __restrict__ pnode) {
    __shared__ unsigned short Az[16][136];   // z rows (bf16), padded
    __shared__ float part[4][16];
    int t = threadIdx.x;
    int wave = t >> 6, lane = t & 63, quad = lane >> 4, fl = lane & 15;
    int nl = wave * 4 + quad;
    int node = blockIdx.x * 16 + nl;
    int2 pack = ((const int2*)(adj + (size_t)node * MAXDEG))[fl];
    int rounds = cnt[node] >> 2;
    float dv = dinv[node];
    int qb = quad << 4;

    float a[8];
#pragma unroll
    for (int j = 0; j < 8; ++j) a[j] = 0.f;

    int i = 0;
    for (; i + 2 <= rounds; i += 2) {
        unsigned pAx = (unsigned)__shfl(pack.x, qb + i, 64);
        unsigned pAy = (unsigned)__shfl(pack.y, qb + i, 64);
        unsigned pBx = (unsigned)__shfl(pack.x, qb + i + 1, 64);
        unsigned pBy = (unsigned)__shfl(pack.y, qb + i + 1, 64);
        u16x8 v0 = *(const u16x8*)(hs + (size_t)(pAx & 0xFFFFu) * 128 + fl * 8);
        u16x8 v1 = *(const u16x8*)(hs + (size_t)(pAx >> 16) * 128 + fl * 8);
        u16x8 v2 = *(const u16x8*)(hs + (size_t)(pAy & 0xFFFFu) * 128 + fl * 8);
        u16x8 v3 = *(const u16x8*)(hs + (size_t)(pAy >> 16) * 128 + fl * 8);
        u16x8 v4 = *(const u16x8*)(hs + (size_t)(pBx & 0xFFFFu) * 128 + fl * 8);
        u16x8 v5 = *(const u16x8*)(hs + (size_t)(pBx >> 16) * 128 + fl * 8);
        u16x8 v6 = *(const u16x8*)(hs + (size_t)(pBy & 0xFFFFu) * 128 + fl * 8);
        u16x8 v7 = *(const u16x8*)(hs + (size_t)(pBy >> 16) * 128 + fl * 8);
#pragma unroll
        for (int j = 0; j < 8; ++j)
            a[j] += ((bu2f(v0[j]) + bu2f(v1[j])) + (bu2f(v2[j]) + bu2f(v3[j])))
                  + ((bu2f(v4[j]) + bu2f(v5[j])) + (bu2f(v6[j]) + bu2f(v7[j])));
    }
    if (i < rounds) {
        unsigned px = (unsigned)__shfl(pack.x, qb + i, 64);
        unsigned py = (unsigned)__shfl(pack.y, qb + i, 64);
        u16x8 v0 = *(const u16x8*)(hs + (size_t)(px & 0xFFFFu) * 128 + fl * 8);
        u16x8 v1 = *(const u16x8*)(hs + (size_t)(px >> 16) * 128 + fl * 8);
        u16x8 v2 = *(const u16x8*)(hs + (size_t)(py & 0xFFFFu) * 128 + fl * 8);
        u16x8 v3 = *(const u16x8*)(hs + (size_t)(py >> 16) * 128 + fl * 8);
#pragma unroll
        for (int j = 0; j < 8; ++j)
            a[j] += (bu2f(v0[j]) + bu2f(v1[j])) + (bu2f(v2[j]) + bu2f(v3[j]));
    }

    u16x8 zv;
#pragma unroll
    for (int j = 0; j < 8; ++j) zv[j] = f2bu(a[j] * dv);
    *(u16x8*)(&Az[nl][fl * 8]) = zv;
    __syncthreads();

    short8 af[4];
#pragma unroll
    for (int ks = 0; ks < 4; ++ks)
        af[ks] = *(const short8*)(&Az[fl][ks * 32 + quad * 8]);

    f32x4 acc[2];
    acc[0] = (f32x4){0.f, 0.f, 0.f, 0.f};
    acc[1] = (f32x4){0.f, 0.f, 0.f, 0.f};
#pragma unroll
    for (int ks = 0; ks < 4; ++ks)
#pragma unroll
        for (int ct = 0; ct < 2; ++ct) {
            short8 b = *(const short8*)(W2t + (size_t)(wave * 32 + ct * 16 + fl) * 128 + ks * 32 + quad * 8);
            acc[ct] = __builtin_amdgcn_mfma_f32_16x16x32_bf16(af[ks], b, acc[ct], 0, 0, 0);
        }

    float p[4];
#pragma unroll
    for (int rr = 0; rr < 4; ++rr) {
        float s = 0.f;
#pragma unroll
        for (int ct = 0; ct < 2; ++ct) {
            int col = wave * 32 + ct * 16 + fl;
            s += fmaxf(acc[ct][rr] + bias[col], 0.f) * Wl[col];
        }
        p[rr] = s;
    }
#pragma unroll
    for (int rr = 0; rr < 4; ++rr) {
        p[rr] += __shfl_xor(p[rr], 1, 64);
        p[rr] += __shfl_xor(p[rr], 2, 64);
        p[rr] += __shfl_xor(p[rr], 4, 64);
        p[rr] += __shfl_xor(p[rr], 8, 64);
    }
    if (fl == 0) {
#pragma unroll
        for (int rr = 0; rr < 4; ++rr) part[wave][quad * 4 + rr] = p[rr];
    }
    __syncthreads();
    if (t < 16)
        pnode[blockIdx.x * 16 + t] = part[0][t] + part[1][t] + part[2][t] + part[3][t];
}

// ---- final: one wave per graph; segment-mean of pnode + bias + sigmoid ----
__device__ __forceinline__ int lb(const int* a, int n, int v) {
    int lo = 0, hi = n;
    while (lo < hi) {
        int m = (lo + hi) >> 1;
        if (a[m] < v) lo = m + 1;
        else hi = m;
    }
    return lo;
}

__global__ __launch_bounds__(64) void final_k(const float* __restrict__ pnode,
                                              const int* __restrict__ batch,
                                              const float* __restrict__ bl,
                                              float* __restrict__ out) {
    int g = blockIdx.x, t = threadIdx.x;
    int lo = lb(batch, N_NODES, g), hi = lb(batch, N_NODES, g + 1);
    float s = 0.f;
    for (int r = lo + t; r < hi; r += 64) s += pnode[r];
#pragma unroll
    for (int o = 32; o > 0; o >>= 1) s += __shfl_down(s, o, 64);
    if (t == 0) {
        float cf = (float)(hi - lo);
        float z = s / fmaxf(cf, 1.f) + bl[0];
        out[g] = 1.f / (1.f + expf(-z));
    }
}

extern "C" void kernel_launch(void* const* d_in, const int* in_sizes, int n_in,
                              void* d_out, int out_size, void* d_ws, size_t ws_size,
                              hipStream_t stream) {
    const float* x = (const float*)d_in[0];
    const int* ei = (const int*)d_in[1];
    const int* batch = (const int*)d_in[2];
    const float* W1 = (const float*)d_in[3];
    const float* b1 = (const float*)d_in[4];
    const float* W2 = (const float*)d_in[5];
    const float* b2 = (const float*)d_in[6];
    const float* Wl = (const float*)d_in[7];
    const float* bl = (const float*)d_in[8];
    float* out = (float*)d_out;

    char* ws = (char*)d_ws;
    unsigned int* staging = (unsigned int*)(ws + 0x0);       // 3.21 MB
    int* cnts_tbl = (int*)(ws + 0x310000);                   // 200704 B
    int* offs_tbl = (int*)(ws + 0x341000);                   // 200704 B
    unsigned short* adj = (unsigned short*)(ws + 0x372000);  // 6.42 MB
    int* cnt = (int*)(ws + 0x992000);                        // 200 KB
    float* dinv = (float*)(ws + 0x9C3000);                   // 200 KB
    unsigned short* W1t = (unsigned short*)(ws + 0x9F4000);  // 32 KB
    unsigned short* W2t = (unsigned short*)(ws + 0x9FC000);  // 32 KB
    float* pnode = (float*)(ws + 0xA04000);                  // 200 KB
    unsigned short* hs1 = (unsigned short*)(ws + 0xA36000);  // (N+1)x128 bf16
    unsigned short* h1 = (unsigned short*)(ws + 0x1672000);  // (N+1)x128 bf16

    bin_k<<<P1_BLOCKS, 256, 0, stream>>>(ei, staging, cnts_tbl, offs_tbl, hs1, h1);
    adjbuild_k<<<NBUCK + 128, 256, 0, stream>>>(staging, cnts_tbl, offs_tbl,
                                                adj, cnt, dinv, W1, W2, W1t, W2t);
    gemm_k<true><<<(N_NODES + 127) / 128, 256, 0, stream>>>(x, W1t, dinv, hs1);
    agg1_k<<<N_NODES / 16, 256, 0, stream>>>(hs1, adj, cnt, dinv, b1, h1);
    agg2_fused_k<<<N_NODES / 16, 256, 0, stream>>>(h1, adj, cnt, dinv, b2, W2t, Wl, pnode);
    final_k<<<NUM_GRAPHS, 64, 0, stream>>>(pnode, batch, bl, out);
}

// Round 8
// 183.632 us; speedup vs baseline: 1.2062x; 1.0275x over previous
//
#include <hip/hip_runtime.h>
#include <hip/hip_bf16.h>

#define N_NODES 50000
#define N_EDGES 800000
#define NUM_GRAPHS 512
#define MAXDEG 64
#define EPB 4096            // edges per phase-1 block
#define P1_BLOCKS 196       // ceil(N_EDGES / EPB)
#define NBUCK 256
#define NPB 196             // nodes per bucket; NPB*NBUCK = 50176 >= N_NODES

typedef short short8 __attribute__((ext_vector_type(8)));
typedef unsigned short u16x8 __attribute__((ext_vector_type(8)));
typedef float f32x4 __attribute__((ext_vector_type(4)));

__device__ __forceinline__ unsigned short f2bu(float f) {
    __hip_bfloat16 h = __float2bfloat16(f);
    return *reinterpret_cast<unsigned short*>(&h);
}
__device__ __forceinline__ float bu2f(unsigned short u) {
    unsigned int v = ((unsigned int)u) << 16;
    float f;
    __builtin_memcpy(&f, &v, 4);
    return f;
}

// ---- phase 1: bucket 4096 edges/block by dst/196 in LDS, write staged
//      bucket-ordered packed edges (coalesced) + per-(bucket,block) tables.
//      Scan via wave-level shfl_up (1 barrier) instead of Hillis-Steele (16).
//      Also zeros hs1/h1 sentinel rows. ----
__global__ __launch_bounds__(256) void bin_k(const int* __restrict__ ei,
                                             unsigned int* __restrict__ staging,
                                             int* __restrict__ cnts_tbl,
                                             int* __restrict__ offs_tbl,
                                             unsigned short* __restrict__ hs1,
                                             unsigned short* __restrict__ h1) {
    __shared__ unsigned int st[EPB];          // 16 KB
    __shared__ int cnt[NBUCK], cur[NBUCK];
    __shared__ int wsum[4];
    int b = blockIdx.x, t = threadIdx.x;
    int lane = t & 63, wave = t >> 6;
    if (b == 0 && t < 64)
        ((unsigned int*)(hs1 + (size_t)N_NODES * 128))[t] = 0u;
    if (b == 1 && t < 64)
        ((unsigned int*)(h1 + (size_t)N_NODES * 128))[t] = 0u;
    cnt[t] = 0;
    __syncthreads();

    int e0 = b * EPB;
    int srcv[16], dstv[16], bk[16];
#pragma unroll
    for (int k = 0; k < 16; ++k) {
        int e = e0 + k * 256 + t;
        bool ok = e < N_EDGES;
        srcv[k] = ok ? ei[e] : 0;
        dstv[k] = ok ? ei[N_EDGES + e] : 0;
        bk[k] = ok ? (dstv[k] / NPB) : -1;
        if (ok) atomicAdd(&cnt[bk[k]], 1);
    }
    __syncthreads();

    // wave-level inclusive scan of cnt[256] -> exclusive prefix
    int v = cnt[t];
    int incl = v;
#pragma unroll
    for (int o = 1; o < 64; o <<= 1) {
        int u = __shfl_up(incl, o, 64);
        if (lane >= o) incl += u;
    }
    if (lane == 63) wsum[wave] = incl;
    __syncthreads();
    int base = 0;
#pragma unroll
    for (int w = 0; w < 3; ++w) base += (w < wave) ? wsum[w] : 0;
    int excl = base + incl - v;
    cur[t] = excl;
    cnts_tbl[t * P1_BLOCKS + b] = v;        // [bucket][block]
    offs_tbl[t * P1_BLOCKS + b] = excl;
    __syncthreads();

#pragma unroll
    for (int k = 0; k < 16; ++k) {
        if (bk[k] >= 0) {
            int pos = atomicAdd(&cur[bk[k]], 1);
            int dl = dstv[k] - bk[k] * NPB;  // < 196, fits 8 bits
            st[pos] = (unsigned int)srcv[k] | ((unsigned int)dl << 16);
        }
    }
    __syncthreads();
    unsigned int* gout = staging + (size_t)b * EPB;
    for (int i = t; i < EPB; i += 256) gout[i] = st[i];
}

// ---- phase 2: bucket b builds padded adjacency for its 196 nodes in LDS.
//      Thread t < 196 owns p1-block t's staged segment directly (no scan,
//      no binary search). Fused: W->bf16^T. cnt[node] stores tot4. ----
__global__ __launch_bounds__(256) void adjbuild_k(const unsigned int* __restrict__ staging,
                                                  const int* __restrict__ cnts_tbl,
                                                  const int* __restrict__ offs_tbl,
                                                  unsigned short* __restrict__ adj,
                                                  int* __restrict__ cnt,
                                                  float* __restrict__ dinv,
                                                  const float* __restrict__ W1,
                                                  const float* __restrict__ W2,
                                                  unsigned short* __restrict__ W1t,
                                                  unsigned short* __restrict__ W2t) {
    int b = blockIdx.x, t = threadIdx.x;
    if (b >= NBUCK) {  // fused weight transpose-convert
        int wb = b - NBUCK;
        const float* W = wb < 64 ? W1 : W2;
        unsigned short* Wt = wb < 64 ? W1t : W2t;
        int idx = (wb & 63) * 256 + t;
        int k = idx >> 7, n = idx & 127;
        Wt[n * 128 + k] = f2bu(W[idx]);
        return;
    }
    __shared__ unsigned short adjL[NPB * MAXDEG];  // 25088 B
    __shared__ int cntL[NPB];

    if (t < NPB) cntL[t] = 0;
    __syncthreads();

    if (t < P1_BLOCKS) {
        int c = cnts_tbl[b * P1_BLOCKS + t];
        int off = offs_tbl[b * P1_BLOCKS + t];
        const unsigned int* seg = staging + (size_t)t * EPB + off;
        for (int f = 0; f < c; ++f) {
            unsigned int p = seg[f];
            int dl = p >> 16;
            int slot = atomicAdd(&cntL[dl], 1);
            if (slot < MAXDEG - 1) adjL[dl * MAXDEG + slot] = (unsigned short)(p & 0xFFFF);
        }
    }
    __syncthreads();

    int nodeBase = b * NPB;
    if (t < NPB) {
        int node = nodeBase + t;
        int cc = cntL[t];
        int ec = cc < MAXDEG - 1 ? cc : MAXDEG - 1;
        adjL[t * MAXDEG + ec] = (unsigned short)node;  // self loop
        int tot = ec + 1, tot4 = (tot + 3) & ~3;
        for (int s = tot; s < tot4; ++s) adjL[t * MAXDEG + s] = (unsigned short)N_NODES;
        if (node < N_NODES) {
            cnt[node] = tot4;                // padded entry count (mult of 4)
            dinv[node] = rsqrtf((float)cc + 1.0f);
        }
    }
    __syncthreads();
    unsigned int* g = (unsigned int*)(adj + (size_t)nodeBase * MAXDEG);
    const unsigned int* l = (const unsigned int*)adjL;
    for (int i = t; i < NPB * MAXDEG / 2; i += 256) g[i] = l[i];
}

// ---- GEMM: C[r][c] = bf16( dinv[r] * sum_k A[r][k]*W[k][c] ), 128 rows/block ----
template <bool F32A>
__global__ __launch_bounds__(256) void gemm_k(const void* __restrict__ Ap,
                                              const unsigned short* __restrict__ Wt,
                                              const float* __restrict__ dinv,
                                              unsigned short* __restrict__ C) {
    __shared__ unsigned short Wl[128 * 136];
    int t = threadIdx.x;
    for (int idx = t; idx < 2048; idx += 256) {
        int n = idx >> 4, c = idx & 15;
        *(u16x8*)(Wl + n * 136 + c * 8) = *(const u16x8*)(Wt + n * 128 + c * 8);
    }
    __syncthreads();

    int wave = t >> 6, lane = t & 63, quad = lane >> 4, ln = lane & 15;
    int rb = blockIdx.x * 128 + wave * 16;

    short8 a[2][4];
#pragma unroll
    for (int mt = 0; mt < 2; ++mt) {
        int r = rb + mt * 64 + ln;
        r = r < N_NODES ? r : N_NODES - 1;
        if (F32A) {
            const float* arow = (const float*)Ap + (size_t)r * 128 + quad * 8;
#pragma unroll
            for (int ks = 0; ks < 4; ++ks) {
                float4 v0 = *(const float4*)(arow + ks * 32);
                float4 v1 = *(const float4*)(arow + ks * 32 + 4);
                short8 av;
                av[0] = (short)f2bu(v0.x); av[1] = (short)f2bu(v0.y);
                av[2] = (short)f2bu(v0.z); av[3] = (short)f2bu(v0.w);
                av[4] = (short)f2bu(v1.x); av[5] = (short)f2bu(v1.y);
                av[6] = (short)f2bu(v1.z); av[7] = (short)f2bu(v1.w);
                a[mt][ks] = av;
            }
        } else {
            const unsigned short* arow = (const unsigned short*)Ap + (size_t)r * 128 + quad * 8;
#pragma unroll
            for (int ks = 0; ks < 4; ++ks) a[mt][ks] = *(const short8*)(arow + ks * 32);
        }
    }

    f32x4 acc[2][8];
#pragma unroll
    for (int mt = 0; mt < 2; ++mt)
#pragma unroll
        for (int ct = 0; ct < 8; ++ct) acc[mt][ct] = (f32x4){0.f, 0.f, 0.f, 0.f};

#pragma unroll
    for (int ks = 0; ks < 4; ++ks)
#pragma unroll
        for (int ct = 0; ct < 8; ++ct) {
            short8 b = *(const short8*)(Wl + (ct * 16 + ln) * 136 + ks * 32 + quad * 8);
            acc[0][ct] = __builtin_amdgcn_mfma_f32_16x16x32_bf16(a[0][ks], b, acc[0][ct], 0, 0, 0);
            acc[1][ct] = __builtin_amdgcn_mfma_f32_16x16x32_bf16(a[1][ks], b, acc[1][ct], 0, 0, 0);
        }

#pragma unroll
    for (int mt = 0; mt < 2; ++mt) {
#pragma unroll
        for (int rr = 0; rr < 4; ++rr) {
            int r = rb + mt * 64 + quad * 4 + rr;
            if (r >= N_NODES) continue;
            float dv = dinv[r];
#pragma unroll
            for (int ct = 0; ct < 8; ++ct)
                C[(size_t)r * 128 + ct * 16 + ln] = f2bu(acc[mt][ct][rr] * dv);
        }
    }
}

// ---- layer-1 aggregation: ONE node per quad (4 nodes/wave, 16/block).
//      Output h1' = dinv[node] * relu(z + b1)  (dinv pre-folded for layer 2). ----
__global__ __launch_bounds__(256) void agg1_k(const unsigned short* __restrict__ hs,
                                              const unsigned short* __restrict__ adj,
                                              const int* __restrict__ cnt,
                                              const float* __restrict__ dinv,
                                              const float* __restrict__ bias,
                                              unsigned short* __restrict__ out) {
    int t = threadIdx.x;
    int wave = t >> 6, lane = t & 63, quad = lane >> 4, fl = lane & 15;
    int node = blockIdx.x * 16 + wave * 4 + quad;      // grid*16 == N_NODES
    int2 pack = ((const int2*)(adj + (size_t)node * MAXDEG))[fl];
    int rounds = cnt[node] >> 2;                       // >= 1 (self loop)
    float dv = dinv[node];
    float4 b0 = *(const float4*)(bias + fl * 8);
    float4 b1 = *(const float4*)(bias + fl * 8 + 4);
    int qb = quad << 4;

    float a[8];
#pragma unroll
    for (int j = 0; j < 8; ++j) a[j] = 0.f;

    int i = 0;
    for (; i + 2 <= rounds; i += 2) {
        unsigned pAx = (unsigned)__shfl(pack.x, qb + i, 64);
        unsigned pAy = (unsigned)__shfl(pack.y, qb + i, 64);
        unsigned pBx = (unsigned)__shfl(pack.x, qb + i + 1, 64);
        unsigned pBy = (unsigned)__shfl(pack.y, qb + i + 1, 64);
        u16x8 v0 = *(const u16x8*)(hs + (size_t)(pAx & 0xFFFFu) * 128 + fl * 8);
        u16x8 v1 = *(const u16x8*)(hs + (size_t)(pAx >> 16) * 128 + fl * 8);
        u16x8 v2 = *(const u16x8*)(hs + (size_t)(pAy & 0xFFFFu) * 128 + fl * 8);
        u16x8 v3 = *(const u16x8*)(hs + (size_t)(pAy >> 16) * 128 + fl * 8);
        u16x8 v4 = *(const u16x8*)(hs + (size_t)(pBx & 0xFFFFu) * 128 + fl * 8);
        u16x8 v5 = *(const u16x8*)(hs + (size_t)(pBx >> 16) * 128 + fl * 8);
        u16x8 v6 = *(const u16x8*)(hs + (size_t)(pBy & 0xFFFFu) * 128 + fl * 8);
        u16x8 v7 = *(const u16x8*)(hs + (size_t)(pBy >> 16) * 128 + fl * 8);
#pragma unroll
        for (int j = 0; j < 8; ++j)
            a[j] += ((bu2f(v0[j]) + bu2f(v1[j])) + (bu2f(v2[j]) + bu2f(v3[j])))
                  + ((bu2f(v4[j]) + bu2f(v5[j])) + (bu2f(v6[j]) + bu2f(v7[j])));
    }
    if (i < rounds) {
        unsigned px = (unsigned)__shfl(pack.x, qb + i, 64);
        unsigned py = (unsigned)__shfl(pack.y, qb + i, 64);
        u16x8 v0 = *(const u16x8*)(hs + (size_t)(px & 0xFFFFu) * 128 + fl * 8);
        u16x8 v1 = *(const u16x8*)(hs + (size_t)(px >> 16) * 128 + fl * 8);
        u16x8 v2 = *(const u16x8*)(hs + (size_t)(py & 0xFFFFu) * 128 + fl * 8);
        u16x8 v3 = *(const u16x8*)(hs + (size_t)(py >> 16) * 128 + fl * 8);
#pragma unroll
        for (int j = 0; j < 8; ++j)
            a[j] += (bu2f(v0[j]) + bu2f(v1[j])) + (bu2f(v2[j]) + bu2f(v3[j]));
    }

    u16x8 o;
    o[0] = f2bu(fmaxf(a[0] * dv + b0.x, 0.f) * dv);
    o[1] = f2bu(fmaxf(a[1] * dv + b0.y, 0.f) * dv);
    o[2] = f2bu(fmaxf(a[2] * dv + b0.z, 0.f) * dv);
    o[3] = f2bu(fmaxf(a[3] * dv + b0.w, 0.f) * dv);
    o[4] = f2bu(fmaxf(a[4] * dv + b1.x, 0.f) * dv);
    o[5] = f2bu(fmaxf(a[5] * dv + b1.y, 0.f) * dv);
    o[6] = f2bu(fmaxf(a[6] * dv + b1.z, 0.f) * dv);
    o[7] = f2bu(fmaxf(a[7] * dv + b1.w, 0.f) * dv);
    *(u16x8*)(out + (size_t)node * 128 + fl * 8) = o;
}

// ---- FUSED layer-2 + readout: gather h1' (dinv[src] pre-folded),
//      z = dv * sum -> LDS tile, MFMA with W2^T, relu(+b2) dot Wl,
//      in-block reduce -> pnode. ----
__global__ __launch_bounds__(256) void agg2_fused_k(const unsigned short* __restrict__ hs,
                                                    const unsigned short* __restrict__ adj,
                                                    const int* __restrict__ cnt,
                                                    const float* __restrict__ dinv,
                                                    const float* __restrict__ bias,
                                                    const unsigned short* __restrict__ W2t,
                                                    const float* __restrict__ Wl,
                                                    float* __restrict__ pnode) {
    __shared__ unsigned short Az[16][136];   // z rows (bf16), padded
    __shared__ float part[4][16];
    int t = threadIdx.x;
    int wave = t >> 6, lane = t & 63, quad = lane >> 4, fl = lane & 15;
    int nl = wave * 4 + quad;
    int node = blockIdx.x * 16 + nl;
    int2 pack = ((const int2*)(adj + (size_t)node * MAXDEG))[fl];
    int rounds = cnt[node] >> 2;
    float dv = dinv[node];
    int qb = quad << 4;

    float a[8];
#pragma unroll
    for (int j = 0; j < 8; ++j) a[j] = 0.f;

    int i = 0;
    for (; i + 2 <= rounds; i += 2) {
        unsigned pAx = (unsigned)__shfl(pack.x, qb + i, 64);
        unsigned pAy = (unsigned)__shfl(pack.y, qb + i, 64);
        unsigned pBx = (unsigned)__shfl(pack.x, qb + i + 1, 64);
        unsigned pBy = (unsigned)__shfl(pack.y, qb + i + 1, 64);
        u16x8 v0 = *(const u16x8*)(hs + (size_t)(pAx & 0xFFFFu) * 128 + fl * 8);
        u16x8 v1 = *(const u16x8*)(hs + (size_t)(pAx >> 16) * 128 + fl * 8);
        u16x8 v2 = *(const u16x8*)(hs + (size_t)(pAy & 0xFFFFu) * 128 + fl * 8);
        u16x8 v3 = *(const u16x8*)(hs + (size_t)(pAy >> 16) * 128 + fl * 8);
        u16x8 v4 = *(const u16x8*)(hs + (size_t)(pBx & 0xFFFFu) * 128 + fl * 8);
        u16x8 v5 = *(const u16x8*)(hs + (size_t)(pBx >> 16) * 128 + fl * 8);
        u16x8 v6 = *(const u16x8*)(hs + (size_t)(pBy & 0xFFFFu) * 128 + fl * 8);
        u16x8 v7 = *(const u16x8*)(hs + (size_t)(pBy >> 16) * 128 + fl * 8);
#pragma unroll
        for (int j = 0; j < 8; ++j)
            a[j] += ((bu2f(v0[j]) + bu2f(v1[j])) + (bu2f(v2[j]) + bu2f(v3[j])))
                  + ((bu2f(v4[j]) + bu2f(v5[j])) + (bu2f(v6[j]) + bu2f(v7[j])));
    }
    if (i < rounds) {
        unsigned px = (unsigned)__shfl(pack.x, qb + i, 64);
        unsigned py = (unsigned)__shfl(pack.y, qb + i, 64);
        u16x8 v0 = *(const u16x8*)(hs + (size_t)(px & 0xFFFFu) * 128 + fl * 8);
        u16x8 v1 = *(const u16x8*)(hs + (size_t)(px >> 16) * 128 + fl * 8);
        u16x8 v2 = *(const u16x8*)(hs + (size_t)(py & 0xFFFFu) * 128 + fl * 8);
        u16x8 v3 = *(const u16x8*)(hs + (size_t)(py >> 16) * 128 + fl * 8);
#pragma unroll
        for (int j = 0; j < 8; ++j)
            a[j] += (bu2f(v0[j]) + bu2f(v1[j])) + (bu2f(v2[j]) + bu2f(v3[j]));
    }

    u16x8 zv;
#pragma unroll
    for (int j = 0; j < 8; ++j) zv[j] = f2bu(a[j] * dv);
    *(u16x8*)(&Az[nl][fl * 8]) = zv;
    __syncthreads();

    short8 af[4];
#pragma unroll
    for (int ks = 0; ks < 4; ++ks)
        af[ks] = *(const short8*)(&Az[fl][ks * 32 + quad * 8]);

    f32x4 acc[2];
    acc[0] = (f32x4){0.f, 0.f, 0.f, 0.f};
    acc[1] = (f32x4){0.f, 0.f, 0.f, 0.f};
#pragma unroll
    for (int ks = 0; ks < 4; ++ks)
#pragma unroll
        for (int ct = 0; ct < 2; ++ct) {
            short8 b = *(const short8*)(W2t + (size_t)(wave * 32 + ct * 16 + fl) * 128 + ks * 32 + quad * 8);
            acc[ct] = __builtin_amdgcn_mfma_f32_16x16x32_bf16(af[ks], b, acc[ct], 0, 0, 0);
        }

    float p[4];
#pragma unroll
    for (int rr = 0; rr < 4; ++rr) {
        float s = 0.f;
#pragma unroll
        for (int ct = 0; ct < 2; ++ct) {
            int col = wave * 32 + ct * 16 + fl;
            s += fmaxf(acc[ct][rr] + bias[col], 0.f) * Wl[col];
        }
        p[rr] = s;
    }
#pragma unroll
    for (int rr = 0; rr < 4; ++rr) {
        p[rr] += __shfl_xor(p[rr], 1, 64);
        p[rr] += __shfl_xor(p[rr], 2, 64);
        p[rr] += __shfl_xor(p[rr], 4, 64);
        p[rr] += __shfl_xor(p[rr], 8, 64);
    }
    if (fl == 0) {
#pragma unroll
        for (int rr = 0; rr < 4; ++rr) part[wave][quad * 4 + rr] = p[rr];
    }
    __syncthreads();
    if (t < 16)
        pnode[blockIdx.x * 16 + t] = part[0][t] + part[1][t] + part[2][t] + part[3][t];
}

// ---- final: one wave per graph; segment-mean of pnode + bias + sigmoid ----
__device__ __forceinline__ int lb(const int* a, int n, int v) {
    int lo = 0, hi = n;
    while (lo < hi) {
        int m = (lo + hi) >> 1;
        if (a[m] < v) lo = m + 1;
        else hi = m;
    }
    return lo;
}

__global__ __launch_bounds__(64) void final_k(const float* __restrict__ pnode,
                                              const int* __restrict__ batch,
                                              const float* __restrict__ bl,
                                              float* __restrict__ out) {
    int g = blockIdx.x, t = threadIdx.x;
    int lo = lb(batch, N_NODES, g), hi = lb(batch, N_NODES, g + 1);
    float s = 0.f;
    for (int r = lo + t; r < hi; r += 64) s += pnode[r];
#pragma unroll
    for (int o = 32; o > 0; o >>= 1) s += __shfl_down(s, o, 64);
    if (t == 0) {
        float cf = (float)(hi - lo);
        float z = s / fmaxf(cf, 1.f) + bl[0];
        out[g] = 1.f / (1.f + expf(-z));
    }
}

extern "C" void kernel_launch(void* const* d_in, const int* in_sizes, int n_in,
                              void* d_out, int out_size, void* d_ws, size_t ws_size,
                              hipStream_t stream) {
    const float* x = (const float*)d_in[0];
    const int* ei = (const int*)d_in[1];
    const int* batch = (const int*)d_in[2];
    const float* W1 = (const float*)d_in[3];
    const float* b1 = (const float*)d_in[4];
    const float* W2 = (const float*)d_in[5];
    const float* b2 = (const float*)d_in[6];
    const float* Wl = (const float*)d_in[7];
    const float* bl = (const float*)d_in[8];
    float* out = (float*)d_out;

    char* ws = (char*)d_ws;
    unsigned int* staging = (unsigned int*)(ws + 0x0);       // 3.21 MB
    int* cnts_tbl = (int*)(ws + 0x310000);                   // 200704 B
    int* offs_tbl = (int*)(ws + 0x341000);                   // 200704 B
    unsigned short* adj = (unsigned short*)(ws + 0x372000);  // 6.42 MB
    int* cnt = (int*)(ws + 0x992000);                        // 200 KB
    float* dinv = (float*)(ws + 0x9C3000);                   // 200 KB
    unsigned short* W1t = (unsigned short*)(ws + 0x9F4000);  // 32 KB
    unsigned short* W2t = (unsigned short*)(ws + 0x9FC000);  // 32 KB
    float* pnode = (float*)(ws + 0xA04000);                  // 200 KB
    unsigned short* hs1 = (unsigned short*)(ws + 0xA36000);  // (N+1)x128 bf16
    unsigned short* h1 = (unsigned short*)(ws + 0x1672000);  // (N+1)x128 bf16

    bin_k<<<P1_BLOCKS, 256, 0, stream>>>(ei, staging, cnts_tbl, offs_tbl, hs1, h1);
    adjbuild_k<<<NBUCK + 128, 256, 0, stream>>>(staging, cnts_tbl, offs_tbl,
                                                adj, cnt, dinv, W1, W2, W1t, W2t);
    gemm_k<true><<<(N_NODES + 127) / 128, 256, 0, stream>>>(x, W1t, dinv, hs1);
    agg1_k<<<N_NODES / 16, 256, 0, stream>>>(hs1, adj, cnt, dinv, b1, h1);
    agg2_fused_k<<<N_NODES / 16, 256, 0, stream>>>(h1, adj, cnt, dinv, b2, W2t, Wl, pnode);
    final_k<<<NUM_GRAPHS, 64, 0, stream>>>(pnode, batch, bl, out);
}